// Round 19
// baseline (188.903 us; speedup 1.0000x reference)
//
#include <hip/hip_runtime.h>

// GraphPooling: B=8, N=3072, D=1024, POOL=3, steps=1024
//  out[b, 2k,   d] = (sum x[b, s..e, d]) / (e-s+1) + 0.006
//  out[b, 2k+1, d] = mean(x[b, 3k:3k+3, d])
//
// Round-18 (resubmit; R18 bench was a GPU-acquisition timeout, no data):
// R14 event-push structure with HALVED chunks for 2x occupancy.
//  R16 post-mortem: streaming K1 (3 loads in flight) LOST to bulk-24
//  (187.2 vs 182.3) -> K1 is latency-bound on x loads; MLP is king.
//  So scale parallelism ACROSS blocks: CHR 24->12, CHW 8->4, NCH 128->256.
//   K1: 2048 blocks (8/CU = full 32 waves/CU, was 16), 12 bulk nt-loads
//       (48 VGPR payload, no spill), half the serial prefix chain.
//   K2: 256-chunk scan, 16 cols x 16 segs per block, 128 blocks (was 64).
//   K4: unchanged except CHR=12 chunk-index math.
//  Same row-add order; finer chunk grouping -> absmax <= 0.004 expected.

constexpr int Bdim  = 8;
constexpr int Nn    = 3072;
constexpr int Dd    = 1024;
constexpr int STEPS = 1024;   // windows
constexpr int CHW   = 4;      // windows per chunk  (was 8)
constexpr int CHR   = 12;     // rows per chunk     (was 24)
constexpr int NCH   = 256;    // STEPS / CHW        (was 128)
constexpr int KT    = 4;      // steps per K4 block
constexpr int NKT   = 256;    // STEPS / KT
constexpr int D4    = Dd / 4; // 256 float4 per row
constexpr int RCAP  = 16;     // max events per row
constexpr float EPS = 0.006f;

constexpr size_t T_E = (size_t)Bdim * 2 * STEPS * Dd;     // 64 MB (floats)
constexpr size_t P_E = (size_t)Bdim * NCH * Dd;           //  8 MB

typedef float nat_f4 __attribute__((ext_vector_type(4)));

__device__ __forceinline__ float4 f4add(float4 a, float4 b) {
    return make_float4(a.x + b.x, a.y + b.y, a.z + b.z, a.w + b.w);
}

__device__ __forceinline__ float4 f4sel(bool c, float4 a, float4 b) {
    return make_float4(c ? a.x : b.x, c ? a.y : b.y,
                       c ? a.z : b.z, c ? a.w : b.w);
}

__device__ __forceinline__ void nt_store(float4 v, float4* p) {
    nat_f4 nv = {v.x, v.y, v.z, v.w};
    __builtin_nontemporal_store(nv, reinterpret_cast<nat_f4*>(p));
}

__device__ __forceinline__ float4 nt_load(const float4* p) {
    nat_f4 nv = __builtin_nontemporal_load(reinterpret_cast<const nat_f4*>(p));
    return make_float4(nv.x, nv.y, nv.z, nv.w);
}

// ---------------- K1: self-bucket + bulk scan + snapshot push ----------
__global__ __launch_bounds__(256)
void k1_scan(const float4* __restrict__ x4, const int* __restrict__ graph,
             float4* __restrict__ out4, float4* __restrict__ T4,
             float4* __restrict__ P4) {
    const int t  = threadIdx.x;          // float4 column 0..255
    const int ch = blockIdx.x;           // 0..255
    const int b  = blockIdx.y;           // 0..7
    const int k0 = ch * CHW;
    const int r0 = ch * CHR;
    const float4 z4 = make_float4(0.f, 0.f, 0.f, 0.f);

    // ---- issue all 12 x row loads first (bulk MLP: proven vs streaming) ----
    const float4* xp = x4 + ((size_t)(b * Nn + r0)) * D4 + t;
    float4 v[CHR];
#pragma unroll
    for (int i = 0; i < CHR; ++i)
        v[i] = nt_load(&xp[(size_t)i * D4]);

    // ---- self-bucket: events (query rows) landing in [r0, r0+CHR) ----
    __shared__ int scnt[CHR];
    __shared__ int lst[CHR][RCAP];
    if (t < CHR) scnt[t] = 0;
    __syncthreads();
    for (int k = t; k < STEPS; k += 256) {
        const int2 se = *reinterpret_cast<const int2*>(
            graph + ((size_t)(b * STEPS + k)) * 2);
        const int js = se.x - r0;                // start snapshot row
        if (js >= 0 && js < CHR) {
            int p = atomicAdd(&scnt[js], 1);
            if (p < RCAP) lst[js][p] = 2 * k;
        }
        const int je = se.y + 1 - r0;            // end snapshot row
        if (je >= 0 && je < CHR) {
            int p = atomicAdd(&scnt[je], 1);
            if (p < RCAP) lst[je][p] = 2 * k + 1;
        }
    }
    __syncthreads();

    // ---- window means -> odd output rows ----
    float4* op = out4 + ((size_t)b * 2 * STEPS) * D4 + t;
#pragma unroll
    for (int wi = 0; wi < CHW; ++wi) {
        float4 w = f4add(f4add(v[3 * wi], v[3 * wi + 1]), v[3 * wi + 2]);
        float4 wm = make_float4(w.x * (1.f / 3.f), w.y * (1.f / 3.f),
                                w.z * (1.f / 3.f), w.w * (1.f / 3.f));
        nt_store(wm, &op[(size_t)(2 * (k0 + wi) + 1) * D4]);
    }

    // ---- within-chunk exclusive prefix; push snapshots at event rows ----
    float4* Tb = T4 + ((size_t)b * 2 * STEPS) * D4 + t;
    float4 run = z4;
#pragma unroll
    for (int j = 0; j < CHR; ++j) {
        const int nj = min(scnt[j], RCAP);       // uniform (LDS broadcast)
        for (int q = 0; q < nj; ++q)             // usually 0 or 1
            Tb[(size_t)lst[j][q] * D4] = run;    // coalesced 4 KB row
        run = f4add(run, v[j]);
    }
    P4[((size_t)b * NCH + ch) * D4 + t] = run;   // chunk total
}

// ---------------- K2: 2-level scan of 256 chunk totals -> prefix O ------
//  block: 16 f4-cols x 16 segs of 16 chunks; 128 blocks (16 x 8)
__global__ __launch_bounds__(256)
void k2_chscan(const float4* __restrict__ P4, float4* __restrict__ O4) {
    __shared__ float4 part[16][17];
    const int cw  = threadIdx.x & 15;          // f4-col within tile
    const int seg = threadIdx.x >> 4;          // 0..15 -> 16 chunks each
    const int col = blockIdx.x * 16 + cw;
    const int b   = blockIdx.y;

    const float4* p = P4 + (size_t)b * NCH * D4 + col;
    float4 v[16];
    float4 sum = make_float4(0.f, 0.f, 0.f, 0.f);
#pragma unroll
    for (int i = 0; i < 16; ++i) {
        v[i] = p[(size_t)(seg * 16 + i) * D4];
        sum = f4add(sum, v[i]);
    }
    part[seg][cw] = sum;
    __syncthreads();
    if (threadIdx.x < 16) {
        float4 run = make_float4(0.f, 0.f, 0.f, 0.f);
#pragma unroll
        for (int s = 0; s < 16; ++s) {
            float4 t2 = part[s][threadIdx.x];
            part[s][threadIdx.x] = run;
            run = f4add(run, t2);
        }
    }
    __syncthreads();
    float4 run = part[seg][cw];
    float4* o = O4 + (size_t)b * (NCH + 1) * D4 + col;
#pragma unroll
    for (int i = 0; i < 16; ++i) {
        o[(size_t)(seg * 16 + i) * D4] = run;
        run = f4add(run, v[i]);
    }
    if (seg == 15) o[(size_t)NCH * D4] = run;  // grand total = c[N]
}

// ---------------- K4: streaming combine ----------------
//  out[2k] = (O[ch(e+1)] + T[2k+1] - O[ch(s)] - T[2k]) * inv + EPS
__global__ __launch_bounds__(256)
void k4_combine(const float4* __restrict__ T4, const float4* __restrict__ O4,
                const int* __restrict__ graph, float4* __restrict__ out4) {
    const int t  = threadIdx.x;
    const int kt = blockIdx.x;                 // 0..255
    const int b  = blockIdx.y;

    const int* gp = graph + ((size_t)(b * STEPS + kt * KT)) * 2;
    const int4 ga = *reinterpret_cast<const int4*>(gp);
    const int4 gb = *reinterpret_cast<const int4*>(gp + 4);
    const int sA[KT] = {ga.x, ga.z, gb.x, gb.z};
    const int eA[KT] = {ga.y, ga.w, gb.y, gb.w};

    const float4* Tb = T4 + (size_t)b * 2 * STEPS * D4 + t;
    const float4* oc = O4 + (size_t)b * (NCH + 1) * D4 + t;
    float4*       ob = out4 + (size_t)b * 2 * STEPS * D4 + t;

    // ---- issue ALL loads before any combine ----
    float4 ts[KT], te[KT], o1[KT], o2[KT];
    int ieA[KT];
    const float4 tot = oc[(size_t)NCH * D4];   // grand total row (hot)
#pragma unroll
    for (int u = 0; u < KT; ++u) {
        const int k = kt * KT + u;
        ts[u] = Tb[(size_t)(2 * k) * D4];      // sequential streaming rows
        te[u] = Tb[(size_t)(2 * k + 1) * D4];
        const int s = sA[u];
        const int ie = eA[u] + 1;  ieA[u] = ie;            // 1..3072
        o1[u] = oc[(size_t)(s / CHR) * D4];                // hot ~8 MB table
        const int c2 = ie < Nn ? ie / CHR : 0;             // clamp (sel'd away)
        o2[u] = oc[(size_t)c2 * D4];
    }

    // ---- combine + store ----
#pragma unroll
    for (int u = 0; u < KT; ++u) {
        float4 cs = f4add(o1[u], ts[u]);
        float4 ce = f4sel(ieA[u] < Nn, f4add(o2[u], te[u]), tot);

        float inv = 1.f / (float)(eA[u] - sA[u] + 1);
        float4 res = make_float4((ce.x - cs.x) * inv + EPS,
                                 (ce.y - cs.y) * inv + EPS,
                                 (ce.z - cs.z) * inv + EPS,
                                 (ce.w - cs.w) * inv + EPS);
        const int k = kt * KT + u;
        nt_store(res, &ob[(size_t)(2 * k) * D4]);   // even output row
    }
}

extern "C" void kernel_launch(void* const* d_in, const int* in_sizes, int n_in,
                              void* d_out, int out_size, void* d_ws, size_t ws_size,
                              hipStream_t stream) {
    const float* x     = (const float*)d_in[0];
    const int*   graph = (const int*)d_in[1];
    float*       out   = (float*)d_out;

    float* T = (float*)d_ws;
    float* P = T + T_E;
    float* O = P + P_E;

    dim3 g1(NCH, Bdim);          // (256, 8) = 2048 blocks
    k1_scan<<<g1, 256, 0, stream>>>((const float4*)x, graph, (float4*)out,
                                    (float4*)T, (float4*)P);
    dim3 g2(D4 / 16, Bdim);      // (16, 8) = 128 blocks
    k2_chscan<<<g2, 256, 0, stream>>>((const float4*)P, (float4*)O);
    dim3 g4(NKT, Bdim);          // (256, 8) = 2048 blocks
    k4_combine<<<g4, 256, 0, stream>>>((const float4*)T, (const float4*)O,
                                       graph, (float4*)out);
}